// Round 8
// baseline (236.659 us; speedup 1.0000x reference)
//
#include <hip/hip_runtime.h>

// ShiftGraph: B=8, C=16, H=W=256, d=5 (r=2), 24 shifts.
// Output (flat float32): edges (B, E, 2) then ws (B, E), E = 1557540.
// edges[b,e] = (pos, pos + di*W + dj); ws[b,e] = -scale * sum_c (x[c,p2]-x[c,p])^2

#define HH 256
#define WW 256
#define CC 16
#define BB 8
#define NSHIFT 24

__global__ __launch_bounds__(256) void shiftgraph_kernel(
    const float* __restrict__ x, float* __restrict__ out, long totalE) {
    const int k = blockIdx.z;           // shift index 0..23
    const int b = blockIdx.y;           // batch
    const int k2 = k + (k >= 12 ? 1 : 0);   // skip center (i=2,j=2)
    const int di = k2 / 5 - 2;
    const int dj = k2 % 5 - 2;
    const int adi = di < 0 ? -di : di;
    const int adj = dj < 0 ? -dj : dj;
    const int chh = HH - adi;
    const int cww = WW - adj;
    const int cnt = chh * cww;

    const int t = blockIdx.x * blockDim.x + threadIdx.x;
    if (t >= cnt) return;

    // offset of this shift's edge block (prefix sum of counts) — scalar, cheap
    int offset = 0;
#pragma unroll
    for (int m = 0; m < NSHIFT; ++m) {
        const int m2 = m + (m >= 12 ? 1 : 0);
        const int mdi = m2 / 5 - 2;
        const int mdj = m2 % 5 - 2;
        const int amdi = mdi < 0 ? -mdi : mdi;
        const int amdj = mdj < 0 ? -mdj : mdj;
        const int c2 = (HH - amdi) * (WW - amdj);
        offset += (m < k) ? c2 : 0;
    }

    const int h0 = di < 0 ? -di : 0;
    const int w0 = dj < 0 ? -dj : 0;
    const int hh = t / cww;
    const int ww = t - hh * cww;
    const int h = h0 + hh;
    const int w = w0 + ww;
    const int pos = h * WW + w;
    const int posv = di * WW + dj;
    const int pos2 = pos + posv;

    const float scale = sqrtf((float)(di * di + dj * dj));

    const float* xb = x + (size_t)b * CC * HH * WW;
    float sum = 0.0f;
#pragma unroll
    for (int c = 0; c < CC; ++c) {
        const float a = xb[(size_t)c * (HH * WW) + pos];
        const float v = xb[(size_t)c * (HH * WW) + pos2];
        const float dd = a - v;
        sum = fmaf(dd, dd, sum);
    }
    const float wsv = -sum * scale;

    const long e = offset + t;
    const size_t eidx = (((size_t)b * totalE + e) << 1);
    out[eidx]     = (float)pos;
    out[eidx + 1] = (float)pos2;
    out[(size_t)BB * totalE * 2 + (size_t)b * totalE + e] = wsv;
}

extern "C" void kernel_launch(void* const* d_in, const int* in_sizes, int n_in,
                              void* d_out, int out_size, void* d_ws, size_t ws_size,
                              hipStream_t stream) {
    const float* x = (const float*)d_in[0];
    float* out = (float*)d_out;
    const long totalE = (long)out_size / (BB * 3);  // = 1557540

    dim3 block(256);
    dim3 grid((HH * WW + 255) / 256, BB, NSHIFT);
    shiftgraph_kernel<<<grid, block, 0, stream>>>(x, out, totalE);
}

// Round 9
// 56.635 us; speedup vs baseline: 4.1786x; 4.1786x over previous
//
#include <hip/hip_runtime.h>

// ShiftGraph: B=8, C=16, H=W=256, d=5 (r=2), 24 shifts.
// Output (flat float32): edges (B, E, 2) then ws (B, E), E = 1557540.
// Restructure vs R0: all 24 shifts computed per (b, row) block -> x read once
// through L1/L2 instead of 24 full sweeps (FETCH was 767 MB = 23x input).
// b = blockIdx.x % 8 pins each batch's 4 MB x-slice to one XCD's 4 MB L2.

#define HH 256
#define WW 256
#define CC 16
#define BB 8
#define EE 1557540   // sum over 24 shifts of (256-|di|)*(256-|dj|) = 1274^2 - 65536

__global__ __launch_bounds__(256) void shiftgraph_kernel(
    const float* __restrict__ x, float* __restrict__ out) {
    const int wg = blockIdx.x;        // 0..2047
    const int b  = wg & 7;            // batch -> XCD (default mapping is n % 8)
    const int h  = wg >> 3;           // row
    const int w  = threadIdx.x;       // col

    const float* __restrict__ xb = x + (size_t)b * (CC * HH * WW);

    // center pixel, all channels, in registers
    float c0[CC];
#pragma unroll
    for (int c = 0; c < CC; ++c)
        c0[c] = xb[c * (HH * WW) + h * WW + w];

    const int pos = h * WW + w;
    float* __restrict__ edges = out;                          // (B, E, 2)
    float* __restrict__ wsout = out + (size_t)BB * EE * 2;    // (B, E)

    int off = 0;   // compile-time constant per (i,j) after full unroll
#pragma unroll
    for (int i = 0; i < 5; ++i) {
#pragma unroll
        for (int j = 0; j < 5; ++j) {
            if (i == 2 && j == 2) continue;
            const int di = i - 2, dj = j - 2;
            const int adi = di < 0 ? -di : di;
            const int adj = dj < 0 ? -dj : dj;
            const int cnt = (HH - adi) * (WW - adj);
            const int h2 = h + di, w2 = w + dj;
            if (h2 >= 0 && h2 < HH && w2 >= 0 && w2 < WW) {
                const int p2 = h2 * WW + w2;
                float sum = 0.0f;
#pragma unroll
                for (int c = 0; c < CC; ++c) {
                    const float d = xb[c * (HH * WW) + p2] - c0[c];
                    sum = fmaf(d, d, sum);
                }
                const float scale = sqrtf((float)(di * di + dj * dj));
                const int h0 = di < 0 ? -di : 0;
                const int w0 = dj < 0 ? -dj : 0;
                const int cww = WW - adj;
                const int e = off + (h - h0) * cww + (w - w0);
                const size_t be = (size_t)b * EE + e;
                const float2 ev = make_float2((float)pos, (float)(pos + di * WW + dj));
                *reinterpret_cast<float2*>(edges + be * 2) = ev;
                wsout[be] = -sum * scale;
            }
            off += cnt;
        }
    }
}

extern "C" void kernel_launch(void* const* d_in, const int* in_sizes, int n_in,
                              void* d_out, int out_size, void* d_ws, size_t ws_size,
                              hipStream_t stream) {
    const float* x = (const float*)d_in[0];
    float* out = (float*)d_out;
    dim3 block(WW);            // one thread per column
    dim3 grid(HH * BB);        // one block per (row, batch)
    shiftgraph_kernel<<<grid, block, 0, stream>>>(x, out);
}